// Round 9
// baseline (4402.769 us; speedup 1.0000x reference)
//
#include <hip/hip_runtime.h>

constexpr int B  = 64;
constexpr int T  = 121;
constexpr int E  = 300;
constexpr int Ep = 320;    // E padded to K-chunk multiple
constexpr int H  = 256;
constexpr int G4 = 1024;   // 4*H
constexpr int D  = 512;    // 2*H
constexpr int NH = 3;
constexpr int BT = B * T;  // 7744
constexpr int Mp = 7808;   // 61*128, M padded for 128-row tiles

using short8 = __attribute__((ext_vector_type(8))) short;
using f32x4  = __attribute__((ext_vector_type(4))) float;

__device__ __forceinline__ float sigmoidf(float x) { return 1.0f / (1.0f + __expf(-x)); }
__device__ __forceinline__ float tanhf_fast(float x) {
  float e = __expf(2.0f * x);
  return 1.0f - 2.0f / (e + 1.0f);
}
__device__ __forceinline__ unsigned bf16rne(float x) {
  unsigned u = __float_as_uint(x);
  return (u + 0x7fffu + ((u >> 16) & 1u)) >> 16;
}
__device__ __forceinline__ float bf_lo(unsigned u) { return __uint_as_float(u << 16); }
__device__ __forceinline__ float bf_hi(unsigned u) { return __uint_as_float(u & 0xffff0000u); }
__device__ __forceinline__ float bfu(unsigned short u) { return __uint_as_float(((unsigned)u) << 16); }

// ---------------- weight packing ----------------
// LSTM: bf16 pair-packed, uint4-grouped (round-4 verified)
__global__ void k_pack_lstm(const float* __restrict__ Wh,
                            uint4* __restrict__ PAQ, uint4* __restrict__ PBQ) {
  int idx = blockIdx.x * 256 + threadIdx.x;   // over (H/4)*256 = 16384
  int k4 = idx >> 8, j = idx & 255;
  int k = 4 * k4;
  uint4 a, bq;
  const float* r0 = Wh + (size_t)(k + 0) * G4;
  const float* r1 = Wh + (size_t)(k + 1) * G4;
  const float* r2 = Wh + (size_t)(k + 2) * G4;
  const float* r3 = Wh + (size_t)(k + 3) * G4;
  a.x  = bf16rne(r0[j]) | (bf16rne(r0[j + 256]) << 16);
  a.y  = bf16rne(r1[j]) | (bf16rne(r1[j + 256]) << 16);
  a.z  = bf16rne(r2[j]) | (bf16rne(r2[j + 256]) << 16);
  a.w  = bf16rne(r3[j]) | (bf16rne(r3[j + 256]) << 16);
  bq.x = bf16rne(r0[j + 512]) | (bf16rne(r0[j + 768]) << 16);
  bq.y = bf16rne(r1[j + 512]) | (bf16rne(r1[j + 768]) << 16);
  bq.z = bf16rne(r2[j + 512]) | (bf16rne(r2[j + 768]) << 16);
  bq.w = bf16rne(r3[j + 512]) | (bf16rne(r3[j + 768]) << 16);
  PAQ[idx] = a;
  PBQ[idx] = bq;
}

// generic B^T bf16 pack with zero padding: WT[n*Kpad + k] = bf16(W[k*stride + n]) or 0
__global__ void k_packT(const float* __restrict__ W, unsigned short* __restrict__ WT,
                        int Ksrc, int Nsrc, int stride, int Kpad) {
  int idx = blockIdx.x * 256 + threadIdx.x;
  int n = idx / Kpad, k = idx - n * Kpad;
  float v = (k < Ksrc && n < Nsrc) ? W[(size_t)k * stride + n] : 0.0f;
  WT[idx] = (unsigned short)bf16rne(v);
}

// pack xr/xc (f32) -> bf16 pair, IN PLACE over xr (no restrict: intentional alias)
__global__ void k_packxrc(const float* xr, const float* xc, unsigned* XRC) {
  size_t i = (size_t)blockIdx.x * 512 + threadIdx.x;
  float r = xr[i], c = xc[i];
  XRC[i] = bf16rne(r) | (bf16rne(c) << 16);
}

// ---------------- embedding gather -> bf16, K-padded ----------------
__global__ void k_gather(const int* __restrict__ tokens, const float* __restrict__ emb,
                         unsigned short* __restrict__ xh) {
  int bt = blockIdx.x;
  int tok = tokens[bt];
  const float* src = emb + (size_t)tok * E;
  unsigned short* dst = xh + (size_t)bt * Ep;
  for (int e = threadIdx.x; e < Ep; e += 256)
    dst[e] = (e < E) ? (unsigned short)bf16rne(src[e]) : (unsigned short)0;
}

// ---------------- bf16 MFMA GEMM (round-6 verified) ----------------
__global__ __launch_bounds__(256) void k_gemm_mfma(
    const unsigned short* __restrict__ A1, const unsigned short* __restrict__ B1, int K1, int lda1,
    const unsigned short* __restrict__ A2, const unsigned short* __restrict__ B2, int K2, int lda2,
    const float* __restrict__ bias, const float* __restrict__ Cin,
    float* __restrict__ C, int Nreal, int Cstride)
{
  __shared__ unsigned short As[128][40];
  __shared__ unsigned short Bs[64][40];
  int tid = threadIdx.x;
  int l = tid & 63, w = tid >> 6;
  int row0 = blockIdx.y * 128, col0 = blockIdx.x * 64;
  int lrow = l & 15, lk = (l >> 4) * 8, lq = (l >> 4) * 4;
  int ar = tid >> 1, asg = (tid & 1) * 16;
  int br = tid >> 2, bsg = (tid & 3) * 8;
  f32x4 acc[2][4] = {};
#pragma unroll 1
  for (int pass = 0; pass < 2; ++pass) {
    const unsigned short* A  = pass ? A2 : A1;
    const unsigned short* Bt = pass ? B2 : B1;
    int K   = pass ? K2 : K1;
    int lda = pass ? lda2 : lda1;
    if (K == 0) break;
    for (int k0 = 0; k0 < K; k0 += 32) {
      const uint4* ga = (const uint4*)(A + (size_t)(row0 + ar) * lda + k0 + asg);
      uint4 a0 = ga[0], a1 = ga[1];
      uint4 b0 = *(const uint4*)(Bt + (size_t)(col0 + br) * K + k0 + bsg);
      __syncthreads();
      *(uint4*)&As[ar][asg]     = a0;
      *(uint4*)&As[ar][asg + 8] = a1;
      *(uint4*)&Bs[br][bsg]     = b0;
      __syncthreads();
      short8 av[2], bv[4];
#pragma unroll
      for (int f = 0; f < 2; ++f)
        av[f] = *(const short8*)&As[w * 32 + f * 16 + lrow][lk];
#pragma unroll
      for (int fc = 0; fc < 4; ++fc)
        bv[fc] = *(const short8*)&Bs[fc * 16 + lrow][lk];
#pragma unroll
      for (int f = 0; f < 2; ++f)
#pragma unroll
        for (int fc = 0; fc < 4; ++fc)
          acc[f][fc] = __builtin_amdgcn_mfma_f32_16x16x32_bf16(av[f], bv[fc], acc[f][fc], 0, 0, 0);
    }
  }
#pragma unroll
  for (int f = 0; f < 2; ++f) {
#pragma unroll
    for (int fc = 0; fc < 4; ++fc) {
      int c = col0 + fc * 16 + lrow;
      if (c < Nreal) {
        float bb = bias ? bias[c] : 0.0f;
#pragma unroll
        for (int i = 0; i < 4; ++i) {
          int r = row0 + w * 32 + f * 16 + lq + i;
          if (r < BT) {
            float v = acc[f][fc][i] + bb;
            if (Cin) v += Cin[(size_t)r * Cstride + c];
            C[(size_t)r * Cstride + c] = v;
          }
        }
      }
    }
  }
}

// ---------------- BiLSTM scan (round-6 verified) ----------------
__global__ __launch_bounds__(512) void k_lstm(
    const float* __restrict__ xp_f, const float* __restrict__ xp_b,
    const uint4* __restrict__ PAQ_f, const uint4* __restrict__ PBQ_f,
    const uint4* __restrict__ PAQ_b, const uint4* __restrict__ PBQ_b,
    const int* __restrict__ lengths, unsigned short* __restrict__ factsh)
{
  int b = blockIdx.x;
  int dir = blockIdx.y;
  const float* xp = dir ? xp_b : xp_f;
  const uint4* PAQ = dir ? PAQ_b : PAQ_f;
  const uint4* PBQ = dir ? PBQ_b : PBQ_f;
  int tid = threadIdx.x;
  int j = tid & 255, half = tid >> 8;
  __shared__ float hs[H];
  __shared__ float4 red[512];
  hs[j] = 0.0f;
  float c = 0.0f, h = 0.0f;
  int nsteps = dir ? T : lengths[b];
  const uint4* pa = PAQ + (size_t)(half * 32) * 256 + j;
  const uint4* pb = PBQ + (size_t)(half * 32) * 256 + j;
  const float4* hs4 = reinterpret_cast<const float4*>(hs) + half * 32;
  __syncthreads();
  for (int s = 0; s < nsteps; ++s) {
    int t = dir ? (T - 1 - s) : s;
    float g0 = 0.f, g1 = 0.f, g2 = 0.f, g3 = 0.f;
#pragma unroll 4
    for (int k4 = 0; k4 < 32; ++k4) {
      uint4 a  = pa[(size_t)k4 * 256];
      uint4 bq = pb[(size_t)k4 * 256];
      float4 hv = hs4[k4];
      g0 = fmaf(hv.x, bf_lo(a.x), g0);  g1 = fmaf(hv.x, bf_hi(a.x), g1);
      g2 = fmaf(hv.x, bf_lo(bq.x), g2); g3 = fmaf(hv.x, bf_hi(bq.x), g3);
      g0 = fmaf(hv.y, bf_lo(a.y), g0);  g1 = fmaf(hv.y, bf_hi(a.y), g1);
      g2 = fmaf(hv.y, bf_lo(bq.y), g2); g3 = fmaf(hv.y, bf_hi(bq.y), g3);
      g0 = fmaf(hv.z, bf_lo(a.z), g0);  g1 = fmaf(hv.z, bf_hi(a.z), g1);
      g2 = fmaf(hv.z, bf_lo(bq.z), g2); g3 = fmaf(hv.z, bf_hi(bq.z), g3);
      g0 = fmaf(hv.w, bf_lo(a.w), g0);  g1 = fmaf(hv.w, bf_hi(a.w), g1);
      g2 = fmaf(hv.w, bf_lo(bq.w), g2); g3 = fmaf(hv.w, bf_hi(bq.w), g3);
    }
    red[tid] = make_float4(g0, g1, g2, g3);
    __syncthreads();
    if (half == 0) {
      float4 o = red[tid + 256];
      const float* xrow = xp + (size_t)(b * T + t) * G4;
      g0 += o.x + xrow[j];
      g1 += o.y + xrow[j + 256];
      g2 += o.z + xrow[j + 512];
      g3 += o.w + xrow[j + 768];
      float ig = sigmoidf(g0);
      float fg = sigmoidf(g1);
      float gg = tanhf_fast(g2);
      float og = sigmoidf(g3);
      c = fg * c + ig * gg;
      h = og * tanhf_fast(c);
      hs[j] = h;
      factsh[(size_t)(b * T + t) * D + dir * H + j] = (unsigned short)bf16rne(h);
    }
    __syncthreads();
  }
}

// ---------------- z halves -> bf16 ----------------
__global__ void k_buildz(const unsigned short* __restrict__ factsh, const float* __restrict__ v,
                         unsigned short* __restrict__ za, unsigned short* __restrict__ zb) {
  int bt = blockIdx.x;
  int b = bt / T;
  int d = threadIdx.x;  // 512
  float f = bfu(factsh[(size_t)bt * D + d]);
  float vv = v[(size_t)b * D + d];
  za[(size_t)bt * D + d] = (unsigned short)bf16rne(f * vv);
  zb[(size_t)bt * D + d] = (unsigned short)bf16rne(fabsf(f - vv));
}

// ---------------- score ----------------
__global__ void k_score(const float* __restrict__ att_h, const float* __restrict__ W2,
                        const float* __restrict__ b2, float* __restrict__ s) {
  int bt = blockIdx.x;
  int tid = threadIdx.x;  // 64
  float acc = 0.f;
  for (int e = tid; e < E; e += 64)
    acc += tanhf_fast(att_h[(size_t)bt * E + e]) * W2[e];
  for (int off = 32; off > 0; off >>= 1) acc += __shfl_down(acc, off);
  if (tid == 0) s[bt] = acc + b2[0];
}

// ---------------- masked softmax ----------------
__global__ void k_softmax(const float* __restrict__ s, const int* __restrict__ lengths,
                          float* __restrict__ a) {
  int b = blockIdx.x;
  int t = threadIdx.x;  // 128
  int len = lengths[b];
  __shared__ float wred[2];
  float val = -1e30f;
  if (t < T) val = (t < len) ? s[b * T + t] : -1e9f;
  float mx = val;
  for (int off = 32; off > 0; off >>= 1) mx = fmaxf(mx, __shfl_xor(mx, off));
  int wid = t >> 6, lane = t & 63;
  if (lane == 0) wred[wid] = mx;
  __syncthreads();
  mx = fmaxf(wred[0], wred[1]);
  __syncthreads();
  float e = (t < T && t < len) ? __expf(val - mx) : 0.0f;
  float sum = e;
  for (int off = 32; off > 0; off >>= 1) sum += __shfl_xor(sum, off);
  if (lane == 0) wred[wid] = sum;
  __syncthreads();
  float tot = wred[0] + wred[1];
  if (t < T) a[b * T + t] = e / tot;
}

// ---------------- zero helpers ----------------
__global__ void k_zero(int* __restrict__ p, int n) {
  int i = blockIdx.x * blockDim.x + threadIdx.x;
  if (i < n) p[i] = 0;
}
__global__ void k_ginit(unsigned short* __restrict__ Hb0) {
  Hb0[blockIdx.x * 512 + threadIdx.x] = 0;
}

// ---------------- persistent GRU hop: 8 blocks x 512 thr, 128KB LDS weights --------
// Block bi owns cols [bi*64, bi*64+64); wave w: s=w>>2 col-half, wb=w&3 batch group.
// Per-wave mapping identical to round-8-verified version. Read-only gate operands
// (XRC bf16-pair, att) are PREFETCHED before the barrier so only Hin loads sit on
// the post-barrier critical path. h state in regs; Hb double-buffered bf16.
__global__ __launch_bounds__(512) void k_gru_hop(
    const unsigned short* __restrict__ URCT,   // [1024][512] bf16: UrT | UcT
    unsigned short* __restrict__ Hb,           // [2][B][D] bf16, Hb[0] pre-zeroed
    float* __restrict__ ep,
    const unsigned* __restrict__ XRC,          // [BT][D] bf16 pair (xr,xc)
    const float* __restrict__ br, const float* __restrict__ bc,
    const float* __restrict__ att, int* __restrict__ syncA)
{
  extern __shared__ unsigned short Wl[];       // 2 sub-slices x 64 x 512 = 128 KB
  const int tid = threadIdx.x;
  const int bi  = blockIdx.x;                  // 0..7
  const int w   = tid >> 6;                    // 0..7
  const int s   = w >> 2;                      // col-half
  const int wb  = w & 3;                       // batch group
  const int l   = tid & 63;
  const int lrow = l & 15, g = l >> 4;
  const int lq  = g * 4;
  const int j0  = bi * 64 + s * 32;
  const unsigned short* WlS = Wl + s * 64 * 512;

  // weights -> LDS (16B-unit XOR swizzle; round-8-verified pattern per sub-slice)
  for (int it = tid; it < 128 * 64; it += 512) {
    int row128 = it >> 6, unit = it & 63;
    int sl = row128 >> 6, row = row128 & 63;
    int jb = bi * 64 + sl * 32;
    int grow = (row < 32) ? (jb + row) : (512 + jb + row - 32);
    uint4 v = *(const uint4*)(URCT + (size_t)grow * 512 + unit * 8);
    *(uint4*)&Wl[sl * 64 * 512 + row * 512 + ((unit ^ (row & 7)) * 8)] = v;
  }

  float brj[2], bcj[2];
#pragma unroll
  for (int fc = 0; fc < 2; ++fc) {
    brj[fc] = br[j0 + fc * 16 + lrow];
    bcj[fc] = bc[j0 + fc * 16 + lrow];
  }

  // prefetch gate operands for t = 0
  unsigned xq[2][4];
  float gv[4];
#pragma unroll
  for (int i = 0; i < 4; ++i) {
    int b = wb * 16 + lq + i;
    gv[i] = att[b * T];
#pragma unroll
    for (int fc = 0; fc < 2; ++fc)
      xq[fc][i] = XRC[(size_t)(b * T) * D + j0 + fc * 16 + lrow];
  }
  __syncthreads();   // weights staged (drains prefetch too — overlapped)

  float h[2][4] = {};
  for (int t = 0; t < T; ++t) {
    const unsigned short* Hin = Hb + (size_t)(t & 1) * (B * D);
    unsigned short*      Hout = Hb + (size_t)((t + 1) & 1) * (B * D);
    // post-barrier critical path: only the H fragments
    uint4 a[16];
#pragma unroll
    for (int c = 0; c < 16; ++c)
      a[c] = *(const uint4*)(Hin + (size_t)(wb * 16 + lrow) * D + c * 32 + g * 8);
    // issue next step's read-only operand loads (hidden under MFMA + barrier drain)
    unsigned xqn[2][4] = {};
    float gvn[4] = {};
    if (t + 1 < T) {
#pragma unroll
      for (int i = 0; i < 4; ++i) {
        int b = wb * 16 + lq + i;
        gvn[i] = att[b * T + t + 1];
#pragma unroll
        for (int fc = 0; fc < 2; ++fc)
          xqn[fc][i] = XRC[(size_t)(b * T + t + 1) * D + j0 + fc * 16 + lrow];
      }
    }
    f32x4 acc[4] = {};
#pragma unroll
    for (int c = 0; c < 16; ++c) {
      short8 av = *(const short8*)&a[c];
#pragma unroll
      for (int fc = 0; fc < 4; ++fc) {
        int row = fc * 16 + lrow;
        short8 bv = *(const short8*)&WlS[row * 512 + (((c * 4 + g) ^ (row & 7)) * 8)];
        acc[fc] = __builtin_amdgcn_mfma_f32_16x16x32_bf16(av, bv, acc[fc], 0, 0, 0);
      }
    }
    // fused gate epilogue: racc at frag fc, cacc at frag fc+2 (same lane/reg)
#pragma unroll
    for (int fc = 0; fc < 2; ++fc) {
#pragma unroll
      for (int i = 0; i < 4; ++i) {
        int b = wb * 16 + lq + i;
        float r  = sigmoidf(bf_lo(xq[fc][i]) + acc[fc][i] + brj[fc]);
        float hc = tanhf_fast(bf_hi(xq[fc][i]) + r * acc[fc + 2][i] + bcj[fc]);
        float hn = gv[i] * hc + (1.f - gv[i]) * h[fc][i];
        h[fc][i] = hn;
        Hout[(size_t)b * D + j0 + fc * 16 + lrow] = (unsigned short)bf16rne(hn);
      }
    }
    // grid barrier (round-8-verified release/acquire; weights fence-immune in LDS)
    __syncthreads();
    if (tid == 0) {
      __threadfence();
      atomicAdd(&syncA[t], 1);
      while (__hip_atomic_load(&syncA[t], __ATOMIC_RELAXED, __HIP_MEMORY_SCOPE_AGENT) < 8)
        __builtin_amdgcn_s_sleep(1);
    }
    __syncthreads();
    __threadfence();
    // rotate prefetched operands
#pragma unroll
    for (int i = 0; i < 4; ++i) {
      gv[i] = gvn[i];
#pragma unroll
      for (int fc = 0; fc < 2; ++fc) xq[fc][i] = xqn[fc][i];
    }
  }
#pragma unroll
  for (int fc = 0; fc < 2; ++fc)
#pragma unroll
    for (int i = 0; i < 4; ++i) {
      int b = wb * 16 + lq + i;
      ep[(size_t)b * D + j0 + fc * 16 + lrow] = h[fc][i];
    }
}

// ---------------- hop projection ----------------
__global__ __launch_bounds__(512) void k_hop(
    const float* __restrict__ m_in, const float* __restrict__ ep,
    const float* __restrict__ q, const float* __restrict__ Whop,
    const float* __restrict__ bhop, float* __restrict__ m_out)
{
  int b = blockIdx.x, j = threadIdx.x;
  __shared__ float av[3 * D];
  av[j]         = m_in[(size_t)b * D + j];
  av[D + j]     = ep[(size_t)b * D + j];
  av[2 * D + j] = q[(size_t)b * D + j];
  __syncthreads();
  float acc = bhop[j];
#pragma unroll 4
  for (int k = 0; k < 3 * D; ++k)
    acc = fmaf(av[k], Whop[(size_t)k * D + j], acc);
  m_out[(size_t)b * D + j] = fmaxf(acc, 0.0f);
}

// ---------------- output ----------------
__global__ void k_out(const float* __restrict__ m, const float* __restrict__ q,
                      const float* __restrict__ Wo, const float* __restrict__ bo,
                      float* __restrict__ out)
{
  int b = blockIdx.x, tid = threadIdx.x;  // 256
  float acc = 0.f;
  for (int k = tid; k < D; k += 256)
    acc += m[(size_t)b * D + k] * Wo[k] + q[(size_t)b * D + k] * Wo[D + k];
  for (int off = 32; off > 0; off >>= 1) acc += __shfl_down(acc, off);
  __shared__ float red[4];
  int wid = tid >> 6, lane = tid & 63;
  if (lane == 0) red[wid] = acc;
  __syncthreads();
  if (tid == 0) {
    float tot = red[0] + red[1] + red[2] + red[3];
    out[b] = 1.0f / (1.0f + __expf(-(tot + bo[0])));
  }
}

extern "C" void kernel_launch(void* const* d_in, const int* in_sizes, int n_in,
                              void* d_out, int out_size, void* d_ws, size_t ws_size,
                              hipStream_t stream)
{
  const int*   tokens  = (const int*)d_in[0];
  const int*   lengths = (const int*)d_in[1];
  const float* emb     = (const float*)d_in[2];
  const float* Wx_f    = (const float*)d_in[3];
  const float* Wh_f    = (const float*)d_in[4];
  const float* b_f     = (const float*)d_in[5];
  const float* Wx_b    = (const float*)d_in[6];
  const float* Wh_b    = (const float*)d_in[7];
  const float* b_b     = (const float*)d_in[8];
  const float* W1      = (const float*)d_in[9];
  const float* b1      = (const float*)d_in[10];
  const float* W2      = (const float*)d_in[11];
  const float* b2      = (const float*)d_in[12];
  const float* Wr      = (const float*)d_in[13];
  const float* Ur      = (const float*)d_in[14];
  const float* br      = (const float*)d_in[15];
  const float* Wc      = (const float*)d_in[16];
  const float* Uc      = (const float*)d_in[17];
  const float* bc      = (const float*)d_in[18];
  const float* q       = (const float*)d_in[19];
  const float* W_hops  = (const float*)d_in[20];
  const float* b_hops  = (const float*)d_in[21];
  const float* Wo      = (const float*)d_in[22];
  const float* bo      = (const float*)d_in[23];
  float* ws = (float*)d_ws;

  // ---- workspace layout ----
  float* p = ws;
  unsigned short* xh = (unsigned short*)p;  p += (size_t)Mp * Ep / 2;
  float* xp_f   = p;  p += (size_t)BT * G4;                                 // later: xr | xc -> XRC
  float* xp_b   = p;  p += (size_t)BT * G4;                                 // later: za | zb
  unsigned short* factsh = (unsigned short*)p;  p += (size_t)Mp * D / 2;
  float* att_h  = p;  p += (size_t)BT * E;
  float* part0  = p;  p += (size_t)BT * E;
  float* scores = p;  p += BT;
  float* att    = p;  p += BT;
  float* m0     = p;  p += (size_t)B * D;
  float* m1     = p;  p += (size_t)B * D;
  float* epb    = p;  p += (size_t)B * D;
  unsigned short* Hb = (unsigned short*)p;  p += (size_t)2 * B * D / 2;     // [2][B][D] bf16
  int* syncA    = (int*)p;  p += 3 * 128;
  uint4* PAQ_f  = (uint4*)p;  p += (size_t)(H / 4) * 256 * 4;
  uint4* PBQ_f  = (uint4*)p;  p += (size_t)(H / 4) * 256 * 4;
  uint4* PAQ_b  = (uint4*)p;  p += (size_t)(H / 4) * 256 * 4;
  uint4* PBQ_b  = (uint4*)p;  p += (size_t)(H / 4) * 256 * 4;
  unsigned short* WxT_f = (unsigned short*)p;  p += (size_t)G4 * Ep / 2;
  unsigned short* WxT_b = (unsigned short*)p;  p += (size_t)G4 * Ep / 2;
  unsigned short* WrT   = (unsigned short*)p;  p += (size_t)D * D / 2;
  unsigned short* WcT   = (unsigned short*)p;  p += (size_t)D * D / 2;
  unsigned short* URCT  = (unsigned short*)p;  p += (size_t)(2 * D) * D / 2; // [1024][512]
  unsigned short* W1T[4];
  for (int c = 0; c < 4; ++c) { W1T[c] = (unsigned short*)p; p += (size_t)Ep * D / 2; }
  float* xr = xp_f;
  float* xc = xp_f + (size_t)BT * D;
  unsigned* XRC = (unsigned*)xr;               // in-place bf16-pair pack over xr
  unsigned short* za = (unsigned short*)xp_b;
  unsigned short* zb = (unsigned short*)xp_b + (size_t)Mp * D;

  // 0) zero barrier counters + pack weights
  k_zero<<<1, 384, 0, stream>>>(syncA, 3 * 128);
  k_pack_lstm<<<(H / 4) * 256 / 256, 256, 0, stream>>>(Wh_f, PAQ_f, PBQ_f);
  k_pack_lstm<<<(H / 4) * 256 / 256, 256, 0, stream>>>(Wh_b, PAQ_b, PBQ_b);
  k_packT<<<G4 * Ep / 256, 256, 0, stream>>>(Wx_f, WxT_f, E, G4, G4, Ep);
  k_packT<<<G4 * Ep / 256, 256, 0, stream>>>(Wx_b, WxT_b, E, G4, G4, Ep);
  k_packT<<<D * D / 256, 256, 0, stream>>>(Wr, WrT, D, D, D, D);
  k_packT<<<D * D / 256, 256, 0, stream>>>(Wc, WcT, D, D, D, D);
  k_packT<<<D * D / 256, 256, 0, stream>>>(Ur, URCT, D, D, D, D);
  k_packT<<<D * D / 256, 256, 0, stream>>>(Uc, URCT + (size_t)D * D, D, D, D, D);
  for (int c = 0; c < 4; ++c)
    k_packT<<<Ep * D / 256, 256, 0, stream>>>(W1 + (size_t)c * D * E, W1T[c], D, E, E, D);

  // 1) embed + input projections (MFMA)
  k_gather<<<BT, 256, 0, stream>>>(tokens, emb, xh);
  k_gemm_mfma<<<dim3(G4 / 64, Mp / 128), 256, 0, stream>>>(
      xh, WxT_f, Ep, Ep, nullptr, nullptr, 0, 0, b_f, nullptr, xp_f, G4, G4);
  k_gemm_mfma<<<dim3(G4 / 64, Mp / 128), 256, 0, stream>>>(
      xh, WxT_b, Ep, Ep, nullptr, nullptr, 0, 0, b_b, nullptr, xp_b, G4, G4);
  // 2) BiLSTM
  k_lstm<<<dim3(B, 2), 512, 0, stream>>>(xp_f, xp_b, PAQ_f, PBQ_f, PAQ_b, PBQ_b, lengths, factsh);
  // 3) hop-invariant precomputes (MFMA); then pack xr/xc -> bf16 pairs in place
  k_gemm_mfma<<<dim3(D / 64, Mp / 128), 256, 0, stream>>>(
      factsh, WrT, D, D, nullptr, nullptr, 0, 0, nullptr, nullptr, xr, D, D);
  k_gemm_mfma<<<dim3(D / 64, Mp / 128), 256, 0, stream>>>(
      factsh, WcT, D, D, nullptr, nullptr, 0, 0, nullptr, nullptr, xc, D, D);
  k_packxrc<<<BT * D / 512, 512, 0, stream>>>(xr, xc, XRC);
  k_buildz<<<BT, 512, 0, stream>>>(factsh, q, za, zb);
  k_gemm_mfma<<<dim3(Ep / 64, Mp / 128), 256, 0, stream>>>(
      za, W1T[0], D, D, zb, W1T[2], D, D, b1, nullptr, part0, E, E);

  // 4) hops
  const float* m_in = q;
  float* mb[2] = {m0, m1};
  for (int i = 0; i < NH; ++i) {
    k_buildz<<<BT, 512, 0, stream>>>(factsh, m_in, za, zb);
    k_gemm_mfma<<<dim3(Ep / 64, Mp / 128), 256, 0, stream>>>(
        za, W1T[1], D, D, zb, W1T[3], D, D, nullptr, part0, att_h, E, E);
    k_score<<<BT, 64, 0, stream>>>(att_h, W2, b2, scores);
    k_softmax<<<B, 128, 0, stream>>>(scores, lengths, att);
    // GRU: single persistent kernel per hop (8 blocks, 128KB dynamic LDS)
    k_ginit<<<B * D / 512, 512, 0, stream>>>(Hb);
    k_gru_hop<<<8, 512, 128 * 512 * sizeof(unsigned short), stream>>>(
        URCT, Hb, epb, XRC, br, bc, att, syncA + i * 128);
    k_hop<<<B, 512, 0, stream>>>(m_in, epb, q,
                                 W_hops + (size_t)i * 3 * D * D, b_hops + (size_t)i * D,
                                 mb[i & 1]);
    m_in = mb[i & 1];
  }
  // 5) output
  k_out<<<B, 256, 0, stream>>>(m_in, q, Wo, bo, (float*)d_out);
}

// Round 10
// 3829.867 us; speedup vs baseline: 1.1496x; 1.1496x over previous
//
#include <hip/hip_runtime.h>

constexpr int B  = 64;
constexpr int T  = 121;
constexpr int E  = 300;
constexpr int Ep = 320;    // E padded to K-chunk multiple
constexpr int H  = 256;
constexpr int G4 = 1024;   // 4*H
constexpr int D  = 512;    // 2*H
constexpr int NH = 3;
constexpr int BT = B * T;  // 7744
constexpr int Mp = 7808;   // 61*128, M padded for 128-row tiles

using short8 = __attribute__((ext_vector_type(8))) short;
using f32x4  = __attribute__((ext_vector_type(4))) float;

__device__ __forceinline__ float sigmoidf(float x) { return 1.0f / (1.0f + __expf(-x)); }
__device__ __forceinline__ float tanhf_fast(float x) {
  float e = __expf(2.0f * x);
  return 1.0f - 2.0f / (e + 1.0f);
}
__device__ __forceinline__ unsigned bf16rne(float x) {
  unsigned u = __float_as_uint(x);
  return (u + 0x7fffu + ((u >> 16) & 1u)) >> 16;
}
__device__ __forceinline__ float bf_lo(unsigned u) { return __uint_as_float(u << 16); }
__device__ __forceinline__ float bf_hi(unsigned u) { return __uint_as_float(u & 0xffff0000u); }
__device__ __forceinline__ float bfu(unsigned short u) { return __uint_as_float(((unsigned)u) << 16); }

// ---------------- weight packing ----------------
// LSTM: bf16 pair-packed, uint4-grouped (round-4 verified)
__global__ void k_pack_lstm(const float* __restrict__ Wh,
                            uint4* __restrict__ PAQ, uint4* __restrict__ PBQ) {
  int idx = blockIdx.x * 256 + threadIdx.x;   // over (H/4)*256 = 16384
  int k4 = idx >> 8, j = idx & 255;
  int k = 4 * k4;
  uint4 a, bq;
  const float* r0 = Wh + (size_t)(k + 0) * G4;
  const float* r1 = Wh + (size_t)(k + 1) * G4;
  const float* r2 = Wh + (size_t)(k + 2) * G4;
  const float* r3 = Wh + (size_t)(k + 3) * G4;
  a.x  = bf16rne(r0[j]) | (bf16rne(r0[j + 256]) << 16);
  a.y  = bf16rne(r1[j]) | (bf16rne(r1[j + 256]) << 16);
  a.z  = bf16rne(r2[j]) | (bf16rne(r2[j + 256]) << 16);
  a.w  = bf16rne(r3[j]) | (bf16rne(r3[j + 256]) << 16);
  bq.x = bf16rne(r0[j + 512]) | (bf16rne(r0[j + 768]) << 16);
  bq.y = bf16rne(r1[j + 512]) | (bf16rne(r1[j + 768]) << 16);
  bq.z = bf16rne(r2[j + 512]) | (bf16rne(r2[j + 768]) << 16);
  bq.w = bf16rne(r3[j + 512]) | (bf16rne(r3[j + 768]) << 16);
  PAQ[idx] = a;
  PBQ[idx] = bq;
}

// generic B^T bf16 pack with zero padding: WT[n*Kpad + k] = bf16(W[k*stride + n]) or 0
__global__ void k_packT(const float* __restrict__ W, unsigned short* __restrict__ WT,
                        int Ksrc, int Nsrc, int stride, int Kpad) {
  int idx = blockIdx.x * 256 + threadIdx.x;
  int n = idx / Kpad, k = idx - n * Kpad;
  float v = (k < Ksrc && n < Nsrc) ? W[(size_t)k * stride + n] : 0.0f;
  WT[idx] = (unsigned short)bf16rne(v);
}

// pack xr/xc (f32) -> bf16 pair, IN PLACE over xr (no restrict: intentional alias)
__global__ void k_packxrc(const float* xr, const float* xc, unsigned* XRC) {
  size_t i = (size_t)blockIdx.x * 512 + threadIdx.x;
  float r = xr[i], c = xc[i];
  XRC[i] = bf16rne(r) | (bf16rne(c) << 16);
}

// ---------------- embedding gather -> bf16, K-padded ----------------
__global__ void k_gather(const int* __restrict__ tokens, const float* __restrict__ emb,
                         unsigned short* __restrict__ xh) {
  int bt = blockIdx.x;
  int tok = tokens[bt];
  const float* src = emb + (size_t)tok * E;
  unsigned short* dst = xh + (size_t)bt * Ep;
  for (int e = threadIdx.x; e < Ep; e += 256)
    dst[e] = (e < E) ? (unsigned short)bf16rne(src[e]) : (unsigned short)0;
}

// ---------------- bf16 MFMA GEMM (round-6 verified) ----------------
__global__ __launch_bounds__(256) void k_gemm_mfma(
    const unsigned short* __restrict__ A1, const unsigned short* __restrict__ B1, int K1, int lda1,
    const unsigned short* __restrict__ A2, const unsigned short* __restrict__ B2, int K2, int lda2,
    const float* __restrict__ bias, const float* __restrict__ Cin,
    float* __restrict__ C, int Nreal, int Cstride)
{
  __shared__ unsigned short As[128][40];
  __shared__ unsigned short Bs[64][40];
  int tid = threadIdx.x;
  int l = tid & 63, w = tid >> 6;
  int row0 = blockIdx.y * 128, col0 = blockIdx.x * 64;
  int lrow = l & 15, lk = (l >> 4) * 8, lq = (l >> 4) * 4;
  int ar = tid >> 1, asg = (tid & 1) * 16;
  int br = tid >> 2, bsg = (tid & 3) * 8;
  f32x4 acc[2][4] = {};
#pragma unroll 1
  for (int pass = 0; pass < 2; ++pass) {
    const unsigned short* A  = pass ? A2 : A1;
    const unsigned short* Bt = pass ? B2 : B1;
    int K   = pass ? K2 : K1;
    int lda = pass ? lda2 : lda1;
    if (K == 0) break;
    for (int k0 = 0; k0 < K; k0 += 32) {
      const uint4* ga = (const uint4*)(A + (size_t)(row0 + ar) * lda + k0 + asg);
      uint4 a0 = ga[0], a1 = ga[1];
      uint4 b0 = *(const uint4*)(Bt + (size_t)(col0 + br) * K + k0 + bsg);
      __syncthreads();
      *(uint4*)&As[ar][asg]     = a0;
      *(uint4*)&As[ar][asg + 8] = a1;
      *(uint4*)&Bs[br][bsg]     = b0;
      __syncthreads();
      short8 av[2], bv[4];
#pragma unroll
      for (int f = 0; f < 2; ++f)
        av[f] = *(const short8*)&As[w * 32 + f * 16 + lrow][lk];
#pragma unroll
      for (int fc = 0; fc < 4; ++fc)
        bv[fc] = *(const short8*)&Bs[fc * 16 + lrow][lk];
#pragma unroll
      for (int f = 0; f < 2; ++f)
#pragma unroll
        for (int fc = 0; fc < 4; ++fc)
          acc[f][fc] = __builtin_amdgcn_mfma_f32_16x16x32_bf16(av[f], bv[fc], acc[f][fc], 0, 0, 0);
    }
  }
#pragma unroll
  for (int f = 0; f < 2; ++f) {
#pragma unroll
    for (int fc = 0; fc < 4; ++fc) {
      int c = col0 + fc * 16 + lrow;
      if (c < Nreal) {
        float bb = bias ? bias[c] : 0.0f;
#pragma unroll
        for (int i = 0; i < 4; ++i) {
          int r = row0 + w * 32 + f * 16 + lq + i;
          if (r < BT) {
            float v = acc[f][fc][i] + bb;
            if (Cin) v += Cin[(size_t)r * Cstride + c];
            C[(size_t)r * Cstride + c] = v;
          }
        }
      }
    }
  }
}

// ---------------- BiLSTM scan (round-6 verified) ----------------
__global__ __launch_bounds__(512) void k_lstm(
    const float* __restrict__ xp_f, const float* __restrict__ xp_b,
    const uint4* __restrict__ PAQ_f, const uint4* __restrict__ PBQ_f,
    const uint4* __restrict__ PAQ_b, const uint4* __restrict__ PBQ_b,
    const int* __restrict__ lengths, unsigned short* __restrict__ factsh)
{
  int b = blockIdx.x;
  int dir = blockIdx.y;
  const float* xp = dir ? xp_b : xp_f;
  const uint4* PAQ = dir ? PAQ_b : PAQ_f;
  const uint4* PBQ = dir ? PBQ_b : PBQ_f;
  int tid = threadIdx.x;
  int j = tid & 255, half = tid >> 8;
  __shared__ float hs[H];
  __shared__ float4 red[512];
  hs[j] = 0.0f;
  float c = 0.0f, h = 0.0f;
  int nsteps = dir ? T : lengths[b];
  const uint4* pa = PAQ + (size_t)(half * 32) * 256 + j;
  const uint4* pb = PBQ + (size_t)(half * 32) * 256 + j;
  const float4* hs4 = reinterpret_cast<const float4*>(hs) + half * 32;
  __syncthreads();
  for (int s = 0; s < nsteps; ++s) {
    int t = dir ? (T - 1 - s) : s;
    float g0 = 0.f, g1 = 0.f, g2 = 0.f, g3 = 0.f;
#pragma unroll 4
    for (int k4 = 0; k4 < 32; ++k4) {
      uint4 a  = pa[(size_t)k4 * 256];
      uint4 bq = pb[(size_t)k4 * 256];
      float4 hv = hs4[k4];
      g0 = fmaf(hv.x, bf_lo(a.x), g0);  g1 = fmaf(hv.x, bf_hi(a.x), g1);
      g2 = fmaf(hv.x, bf_lo(bq.x), g2); g3 = fmaf(hv.x, bf_hi(bq.x), g3);
      g0 = fmaf(hv.y, bf_lo(a.y), g0);  g1 = fmaf(hv.y, bf_hi(a.y), g1);
      g2 = fmaf(hv.y, bf_lo(bq.y), g2); g3 = fmaf(hv.y, bf_hi(bq.y), g3);
      g0 = fmaf(hv.z, bf_lo(a.z), g0);  g1 = fmaf(hv.z, bf_hi(a.z), g1);
      g2 = fmaf(hv.z, bf_lo(bq.z), g2); g3 = fmaf(hv.z, bf_hi(bq.z), g3);
      g0 = fmaf(hv.w, bf_lo(a.w), g0);  g1 = fmaf(hv.w, bf_hi(a.w), g1);
      g2 = fmaf(hv.w, bf_lo(bq.w), g2); g3 = fmaf(hv.w, bf_hi(bq.w), g3);
    }
    red[tid] = make_float4(g0, g1, g2, g3);
    __syncthreads();
    if (half == 0) {
      float4 o = red[tid + 256];
      const float* xrow = xp + (size_t)(b * T + t) * G4;
      g0 += o.x + xrow[j];
      g1 += o.y + xrow[j + 256];
      g2 += o.z + xrow[j + 512];
      g3 += o.w + xrow[j + 768];
      float ig = sigmoidf(g0);
      float fg = sigmoidf(g1);
      float gg = tanhf_fast(g2);
      float og = sigmoidf(g3);
      c = fg * c + ig * gg;
      h = og * tanhf_fast(c);
      hs[j] = h;
      factsh[(size_t)(b * T + t) * D + dir * H + j] = (unsigned short)bf16rne(h);
    }
    __syncthreads();
  }
}

// ---------------- z halves -> bf16 ----------------
__global__ void k_buildz(const unsigned short* __restrict__ factsh, const float* __restrict__ v,
                         unsigned short* __restrict__ za, unsigned short* __restrict__ zb) {
  int bt = blockIdx.x;
  int b = bt / T;
  int d = threadIdx.x;  // 512
  float f = bfu(factsh[(size_t)bt * D + d]);
  float vv = v[(size_t)b * D + d];
  za[(size_t)bt * D + d] = (unsigned short)bf16rne(f * vv);
  zb[(size_t)bt * D + d] = (unsigned short)bf16rne(fabsf(f - vv));
}

// ---------------- score ----------------
__global__ void k_score(const float* __restrict__ att_h, const float* __restrict__ W2,
                        const float* __restrict__ b2, float* __restrict__ s) {
  int bt = blockIdx.x;
  int tid = threadIdx.x;  // 64
  float acc = 0.f;
  for (int e = tid; e < E; e += 64)
    acc += tanhf_fast(att_h[(size_t)bt * E + e]) * W2[e];
  for (int off = 32; off > 0; off >>= 1) acc += __shfl_down(acc, off);
  if (tid == 0) s[bt] = acc + b2[0];
}

// ---------------- masked softmax ----------------
__global__ void k_softmax(const float* __restrict__ s, const int* __restrict__ lengths,
                          float* __restrict__ a) {
  int b = blockIdx.x;
  int t = threadIdx.x;  // 128
  int len = lengths[b];
  __shared__ float wred[2];
  float val = -1e30f;
  if (t < T) val = (t < len) ? s[b * T + t] : -1e9f;
  float mx = val;
  for (int off = 32; off > 0; off >>= 1) mx = fmaxf(mx, __shfl_xor(mx, off));
  int wid = t >> 6, lane = t & 63;
  if (lane == 0) wred[wid] = mx;
  __syncthreads();
  mx = fmaxf(wred[0], wred[1]);
  __syncthreads();
  float e = (t < T && t < len) ? __expf(val - mx) : 0.0f;
  float sum = e;
  for (int off = 32; off > 0; off >>= 1) sum += __shfl_xor(sum, off);
  if (lane == 0) wred[wid] = sum;
  __syncthreads();
  float tot = wred[0] + wred[1];
  if (t < T) a[b * T + t] = e / tot;
}

// ---------------- zero helpers ----------------
__global__ void k_zero(int* __restrict__ p, int n) {
  int i = blockIdx.x * blockDim.x + threadIdx.x;
  if (i < n) p[i] = 0;
}
__global__ void k_ginit(unsigned short* __restrict__ Hb0) {
  Hb0[blockIdx.x * 512 + threadIdx.x] = 0;
}

// ---------------- persistent GRU hop: 32 blocks x 256 thr, 32KB LDS weights --------
// Block bi owns cols [bi*16, bi*16+16) for all 64 batches; wave w = batch group.
// LDS rows 0..15 = UrT rows j0.., rows 16..31 = UcT rows j0.. (16B-unit XOR swizzle,
// round-8-verified). acc[0]=racc, acc[1]=cacc land in same lane/reg -> fused gate.
// Read-only operands (XRC bf16 pair, att) prefetched before the barrier; only Hin
// loads sit on the post-barrier critical path. 32 CUs give 2x round-8 miss MLP.
__global__ __launch_bounds__(256) void k_gru_hop(
    const unsigned short* __restrict__ URCT,   // [1024][512] bf16: UrT | UcT
    unsigned short* __restrict__ Hb,           // [2][B][D] bf16, Hb[0] pre-zeroed
    float* __restrict__ ep,
    const unsigned* __restrict__ XRC,          // [BT][D] bf16 pair (xr,xc)
    const float* __restrict__ br, const float* __restrict__ bc,
    const float* __restrict__ att, int* __restrict__ syncA)
{
  __shared__ unsigned short Wl[32 * 512];      // 32 KB
  const int tid = threadIdx.x;
  const int bi  = blockIdx.x;                  // 0..31
  const int j0  = bi * 16;
  const int w   = tid >> 6;                    // batch group 0..3
  const int l   = tid & 63;
  const int lrow = l & 15, g = l >> 4;
  const int lq  = g * 4;
  const int j   = j0 + lrow;

  // weights -> LDS (16B-unit XOR swizzle)
  for (int it = tid; it < 32 * 64; it += 256) {
    int row = it >> 6, unit = it & 63;
    int grow = (row < 16) ? (j0 + row) : (512 + j0 + row - 16);
    uint4 v = *(const uint4*)(URCT + (size_t)grow * 512 + unit * 8);
    *(uint4*)&Wl[row * 512 + ((unit ^ (row & 7)) * 8)] = v;
  }

  const float brj = br[j], bcj = bc[j];

  // prefetch gate operands for t = 0
  unsigned xq[4];
  float gv[4];
#pragma unroll
  for (int i = 0; i < 4; ++i) {
    int b = w * 16 + lq + i;
    gv[i] = att[b * T];
    xq[i] = XRC[(size_t)(b * T) * D + j];
  }
  __syncthreads();   // weights staged (drains prefetch too — overlapped)

  float h[4] = {};
  for (int t = 0; t < T; ++t) {
    const unsigned short* Hin = Hb + (size_t)(t & 1) * (B * D);
    unsigned short*      Hout = Hb + (size_t)((t + 1) & 1) * (B * D);
    // post-barrier critical path: only the H fragments
    uint4 a[16];
#pragma unroll
    for (int c = 0; c < 16; ++c)
      a[c] = *(const uint4*)(Hin + (size_t)(w * 16 + lrow) * D + c * 32 + g * 8);
    // issue next step's read-only operand loads (hidden under MFMA + barrier drain)
    unsigned xqn[4] = {};
    float gvn[4] = {};
    if (t + 1 < T) {
#pragma unroll
      for (int i = 0; i < 4; ++i) {
        int b = w * 16 + lq + i;
        gvn[i] = att[b * T + t + 1];
        xqn[i] = XRC[(size_t)(b * T + t + 1) * D + j];
      }
    }
    f32x4 acc[2] = {};
#pragma unroll
    for (int c = 0; c < 16; ++c) {
      short8 av = *(const short8*)&a[c];
#pragma unroll
      for (int fc = 0; fc < 2; ++fc) {
        int row = fc * 16 + lrow;
        short8 bv = *(const short8*)&Wl[row * 512 + (((c * 4 + g) ^ (row & 7)) * 8)];
        acc[fc] = __builtin_amdgcn_mfma_f32_16x16x32_bf16(av, bv, acc[fc], 0, 0, 0);
      }
    }
    // fused gate epilogue: racc = acc[0], cacc = acc[1] (same lane/reg)
#pragma unroll
    for (int i = 0; i < 4; ++i) {
      int b = w * 16 + lq + i;
      float r  = sigmoidf(bf_lo(xq[i]) + acc[0][i] + brj);
      float hc = tanhf_fast(bf_hi(xq[i]) + r * acc[1][i] + bcj);
      float hn = gv[i] * hc + (1.f - gv[i]) * h[i];
      h[i] = hn;
      Hout[(size_t)b * D + j] = (unsigned short)bf16rne(hn);
    }
    // grid barrier (round-8-verified release/acquire; weights fence-immune in LDS)
    __syncthreads();
    if (tid == 0) {
      __threadfence();
      atomicAdd(&syncA[t], 1);
      while (__hip_atomic_load(&syncA[t], __ATOMIC_RELAXED, __HIP_MEMORY_SCOPE_AGENT) < 32)
        __builtin_amdgcn_s_sleep(1);
    }
    __syncthreads();
    __threadfence();
    // rotate prefetched operands
#pragma unroll
    for (int i = 0; i < 4; ++i) { gv[i] = gvn[i]; xq[i] = xqn[i]; }
  }
#pragma unroll
  for (int i = 0; i < 4; ++i) {
    int b = w * 16 + lq + i;
    ep[(size_t)b * D + j] = h[i];
  }
}

// ---------------- hop projection ----------------
__global__ __launch_bounds__(512) void k_hop(
    const float* __restrict__ m_in, const float* __restrict__ ep,
    const float* __restrict__ q, const float* __restrict__ Whop,
    const float* __restrict__ bhop, float* __restrict__ m_out)
{
  int b = blockIdx.x, j = threadIdx.x;
  __shared__ float av[3 * D];
  av[j]         = m_in[(size_t)b * D + j];
  av[D + j]     = ep[(size_t)b * D + j];
  av[2 * D + j] = q[(size_t)b * D + j];
  __syncthreads();
  float acc = bhop[j];
#pragma unroll 4
  for (int k = 0; k < 3 * D; ++k)
    acc = fmaf(av[k], Whop[(size_t)k * D + j], acc);
  m_out[(size_t)b * D + j] = fmaxf(acc, 0.0f);
}

// ---------------- output ----------------
__global__ void k_out(const float* __restrict__ m, const float* __restrict__ q,
                      const float* __restrict__ Wo, const float* __restrict__ bo,
                      float* __restrict__ out)
{
  int b = blockIdx.x, tid = threadIdx.x;  // 256
  float acc = 0.f;
  for (int k = tid; k < D; k += 256)
    acc += m[(size_t)b * D + k] * Wo[k] + q[(size_t)b * D + k] * Wo[D + k];
  for (int off = 32; off > 0; off >>= 1) acc += __shfl_down(acc, off);
  __shared__ float red[4];
  int wid = tid >> 6, lane = tid & 63;
  if (lane == 0) red[wid] = acc;
  __syncthreads();
  if (tid == 0) {
    float tot = red[0] + red[1] + red[2] + red[3];
    out[b] = 1.0f / (1.0f + __expf(-(tot + bo[0])));
  }
}

extern "C" void kernel_launch(void* const* d_in, const int* in_sizes, int n_in,
                              void* d_out, int out_size, void* d_ws, size_t ws_size,
                              hipStream_t stream)
{
  const int*   tokens  = (const int*)d_in[0];
  const int*   lengths = (const int*)d_in[1];
  const float* emb     = (const float*)d_in[2];
  const float* Wx_f    = (const float*)d_in[3];
  const float* Wh_f    = (const float*)d_in[4];
  const float* b_f     = (const float*)d_in[5];
  const float* Wx_b    = (const float*)d_in[6];
  const float* Wh_b    = (const float*)d_in[7];
  const float* b_b     = (const float*)d_in[8];
  const float* W1      = (const float*)d_in[9];
  const float* b1      = (const float*)d_in[10];
  const float* W2      = (const float*)d_in[11];
  const float* b2      = (const float*)d_in[12];
  const float* Wr      = (const float*)d_in[13];
  const float* Ur      = (const float*)d_in[14];
  const float* br      = (const float*)d_in[15];
  const float* Wc      = (const float*)d_in[16];
  const float* Uc      = (const float*)d_in[17];
  const float* bc      = (const float*)d_in[18];
  const float* q       = (const float*)d_in[19];
  const float* W_hops  = (const float*)d_in[20];
  const float* b_hops  = (const float*)d_in[21];
  const float* Wo      = (const float*)d_in[22];
  const float* bo      = (const float*)d_in[23];
  float* ws = (float*)d_ws;

  // ---- workspace layout ----
  float* p = ws;
  unsigned short* xh = (unsigned short*)p;  p += (size_t)Mp * Ep / 2;
  float* xp_f   = p;  p += (size_t)BT * G4;                                 // later: xr | xc -> XRC
  float* xp_b   = p;  p += (size_t)BT * G4;                                 // later: za | zb
  unsigned short* factsh = (unsigned short*)p;  p += (size_t)Mp * D / 2;
  float* att_h  = p;  p += (size_t)BT * E;
  float* part0  = p;  p += (size_t)BT * E;
  float* scores = p;  p += BT;
  float* att    = p;  p += BT;
  float* m0     = p;  p += (size_t)B * D;
  float* m1     = p;  p += (size_t)B * D;
  float* epb    = p;  p += (size_t)B * D;
  unsigned short* Hb = (unsigned short*)p;  p += (size_t)2 * B * D / 2;     // [2][B][D] bf16
  int* syncA    = (int*)p;  p += 3 * 128;
  uint4* PAQ_f  = (uint4*)p;  p += (size_t)(H / 4) * 256 * 4;
  uint4* PBQ_f  = (uint4*)p;  p += (size_t)(H / 4) * 256 * 4;
  uint4* PAQ_b  = (uint4*)p;  p += (size_t)(H / 4) * 256 * 4;
  uint4* PBQ_b  = (uint4*)p;  p += (size_t)(H / 4) * 256 * 4;
  unsigned short* WxT_f = (unsigned short*)p;  p += (size_t)G4 * Ep / 2;
  unsigned short* WxT_b = (unsigned short*)p;  p += (size_t)G4 * Ep / 2;
  unsigned short* WrT   = (unsigned short*)p;  p += (size_t)D * D / 2;
  unsigned short* WcT   = (unsigned short*)p;  p += (size_t)D * D / 2;
  unsigned short* URCT  = (unsigned short*)p;  p += (size_t)(2 * D) * D / 2; // [1024][512]
  unsigned short* W1T[4];
  for (int c = 0; c < 4; ++c) { W1T[c] = (unsigned short*)p; p += (size_t)Ep * D / 2; }
  float* xr = xp_f;
  float* xc = xp_f + (size_t)BT * D;
  unsigned* XRC = (unsigned*)xr;               // in-place bf16-pair pack over xr
  unsigned short* za = (unsigned short*)xp_b;
  unsigned short* zb = (unsigned short*)xp_b + (size_t)Mp * D;

  // 0) zero barrier counters + pack weights
  k_zero<<<1, 384, 0, stream>>>(syncA, 3 * 128);
  k_pack_lstm<<<(H / 4) * 256 / 256, 256, 0, stream>>>(Wh_f, PAQ_f, PBQ_f);
  k_pack_lstm<<<(H / 4) * 256 / 256, 256, 0, stream>>>(Wh_b, PAQ_b, PBQ_b);
  k_packT<<<G4 * Ep / 256, 256, 0, stream>>>(Wx_f, WxT_f, E, G4, G4, Ep);
  k_packT<<<G4 * Ep / 256, 256, 0, stream>>>(Wx_b, WxT_b, E, G4, G4, Ep);
  k_packT<<<D * D / 256, 256, 0, stream>>>(Wr, WrT, D, D, D, D);
  k_packT<<<D * D / 256, 256, 0, stream>>>(Wc, WcT, D, D, D, D);
  k_packT<<<D * D / 256, 256, 0, stream>>>(Ur, URCT, D, D, D, D);
  k_packT<<<D * D / 256, 256, 0, stream>>>(Uc, URCT + (size_t)D * D, D, D, D, D);
  for (int c = 0; c < 4; ++c)
    k_packT<<<Ep * D / 256, 256, 0, stream>>>(W1 + (size_t)c * D * E, W1T[c], D, E, E, D);

  // 1) embed + input projections (MFMA)
  k_gather<<<BT, 256, 0, stream>>>(tokens, emb, xh);
  k_gemm_mfma<<<dim3(G4 / 64, Mp / 128), 256, 0, stream>>>(
      xh, WxT_f, Ep, Ep, nullptr, nullptr, 0, 0, b_f, nullptr, xp_f, G4, G4);
  k_gemm_mfma<<<dim3(G4 / 64, Mp / 128), 256, 0, stream>>>(
      xh, WxT_b, Ep, Ep, nullptr, nullptr, 0, 0, b_b, nullptr, xp_b, G4, G4);
  // 2) BiLSTM
  k_lstm<<<dim3(B, 2), 512, 0, stream>>>(xp_f, xp_b, PAQ_f, PBQ_f, PAQ_b, PBQ_b, lengths, factsh);
  // 3) hop-invariant precomputes (MFMA); then pack xr/xc -> bf16 pairs in place
  k_gemm_mfma<<<dim3(D / 64, Mp / 128), 256, 0, stream>>>(
      factsh, WrT, D, D, nullptr, nullptr, 0, 0, nullptr, nullptr, xr, D, D);
  k_gemm_mfma<<<dim3(D / 64, Mp / 128), 256, 0, stream>>>(
      factsh, WcT, D, D, nullptr, nullptr, 0, 0, nullptr, nullptr, xc, D, D);
  k_packxrc<<<BT * D / 512, 512, 0, stream>>>(xr, xc, XRC);
  k_buildz<<<BT, 512, 0, stream>>>(factsh, q, za, zb);
  k_gemm_mfma<<<dim3(Ep / 64, Mp / 128), 256, 0, stream>>>(
      za, W1T[0], D, D, zb, W1T[2], D, D, b1, nullptr, part0, E, E);

  // 4) hops
  const float* m_in = q;
  float* mb[2] = {m0, m1};
  for (int i = 0; i < NH; ++i) {
    k_buildz<<<BT, 512, 0, stream>>>(factsh, m_in, za, zb);
    k_gemm_mfma<<<dim3(Ep / 64, Mp / 128), 256, 0, stream>>>(
        za, W1T[1], D, D, zb, W1T[3], D, D, nullptr, part0, att_h, E, E);
    k_score<<<BT, 64, 0, stream>>>(att_h, W2, b2, scores);
    k_softmax<<<B, 128, 0, stream>>>(scores, lengths, att);
    // GRU: single persistent kernel per hop (32 blocks, static 32KB LDS)
    k_ginit<<<B * D / 512, 512, 0, stream>>>(Hb);
    k_gru_hop<<<32, 256, 0, stream>>>(URCT, Hb, epb, XRC, br, bc, att, syncA + i * 128);
    k_hop<<<B, 512, 0, stream>>>(m_in, epb, q,
                                 W_hops + (size_t)i * 3 * D * D, b_hops + (size_t)i * D,
                                 mb[i & 1]);
    m_in = mb[i & 1];
  }
  // 5) output
  k_out<<<B, 256, 0, stream>>>(m_in, q, Wo, bo, (float*)d_out);
}

// Round 11
// 3790.162 us; speedup vs baseline: 1.1616x; 1.0105x over previous
//
#include <hip/hip_runtime.h>

constexpr int B  = 64;
constexpr int T  = 121;
constexpr int E  = 300;
constexpr int Ep = 320;    // E padded to K-chunk multiple
constexpr int H  = 256;
constexpr int G4 = 1024;   // 4*H
constexpr int D  = 512;    // 2*H
constexpr int NH = 3;
constexpr int BT = B * T;  // 7744
constexpr int Mp = 7808;   // 61*128, M padded for 128-row tiles

using short8 = __attribute__((ext_vector_type(8))) short;
using f32x4  = __attribute__((ext_vector_type(4))) float;

__device__ __forceinline__ float sigmoidf(float x) { return 1.0f / (1.0f + __expf(-x)); }
__device__ __forceinline__ float tanhf_fast(float x) {
  float e = __expf(2.0f * x);
  return 1.0f - 2.0f / (e + 1.0f);
}
__device__ __forceinline__ unsigned bf16rne(float x) {
  unsigned u = __float_as_uint(x);
  return (u + 0x7fffu + ((u >> 16) & 1u)) >> 16;
}
__device__ __forceinline__ float bf_lo(unsigned u) { return __uint_as_float(u << 16); }
__device__ __forceinline__ float bf_hi(unsigned u) { return __uint_as_float(u & 0xffff0000u); }
__device__ __forceinline__ float bfu(unsigned short u) { return __uint_as_float(((unsigned)u) << 16); }

// ---------------- weight packing ----------------
// LSTM: bf16 pair-packed, uint4-grouped (round-4 verified)
__global__ void k_pack_lstm(const float* __restrict__ Wh,
                            uint4* __restrict__ PAQ, uint4* __restrict__ PBQ) {
  int idx = blockIdx.x * 256 + threadIdx.x;   // over (H/4)*256 = 16384
  int k4 = idx >> 8, j = idx & 255;
  int k = 4 * k4;
  uint4 a, bq;
  const float* r0 = Wh + (size_t)(k + 0) * G4;
  const float* r1 = Wh + (size_t)(k + 1) * G4;
  const float* r2 = Wh + (size_t)(k + 2) * G4;
  const float* r3 = Wh + (size_t)(k + 3) * G4;
  a.x  = bf16rne(r0[j]) | (bf16rne(r0[j + 256]) << 16);
  a.y  = bf16rne(r1[j]) | (bf16rne(r1[j + 256]) << 16);
  a.z  = bf16rne(r2[j]) | (bf16rne(r2[j + 256]) << 16);
  a.w  = bf16rne(r3[j]) | (bf16rne(r3[j + 256]) << 16);
  bq.x = bf16rne(r0[j + 512]) | (bf16rne(r0[j + 768]) << 16);
  bq.y = bf16rne(r1[j + 512]) | (bf16rne(r1[j + 768]) << 16);
  bq.z = bf16rne(r2[j + 512]) | (bf16rne(r2[j + 768]) << 16);
  bq.w = bf16rne(r3[j + 512]) | (bf16rne(r3[j + 768]) << 16);
  PAQ[idx] = a;
  PBQ[idx] = bq;
}

// generic B^T bf16 pack with zero padding: WT[n*Kpad + k] = bf16(W[k*stride + n]) or 0
__global__ void k_packT(const float* __restrict__ W, unsigned short* __restrict__ WT,
                        int Ksrc, int Nsrc, int stride, int Kpad) {
  int idx = blockIdx.x * 256 + threadIdx.x;
  int n = idx / Kpad, k = idx - n * Kpad;
  float v = (k < Ksrc && n < Nsrc) ? W[(size_t)k * stride + n] : 0.0f;
  WT[idx] = (unsigned short)bf16rne(v);
}

// pack xr/xc (f32) -> bf16 pair, IN PLACE over xr (no restrict: intentional alias)
__global__ void k_packxrc(const float* xr, const float* xc, unsigned* XRC) {
  size_t i = (size_t)blockIdx.x * 512 + threadIdx.x;
  float r = xr[i], c = xc[i];
  XRC[i] = bf16rne(r) | (bf16rne(c) << 16);
}

// ---------------- embedding gather -> bf16, K-padded ----------------
__global__ void k_gather(const int* __restrict__ tokens, const float* __restrict__ emb,
                         unsigned short* __restrict__ xh) {
  int bt = blockIdx.x;
  int tok = tokens[bt];
  const float* src = emb + (size_t)tok * E;
  unsigned short* dst = xh + (size_t)bt * Ep;
  for (int e = threadIdx.x; e < Ep; e += 256)
    dst[e] = (e < E) ? (unsigned short)bf16rne(src[e]) : (unsigned short)0;
}

// ---------------- bf16 MFMA GEMM (round-6 verified) ----------------
__global__ __launch_bounds__(256) void k_gemm_mfma(
    const unsigned short* __restrict__ A1, const unsigned short* __restrict__ B1, int K1, int lda1,
    const unsigned short* __restrict__ A2, const unsigned short* __restrict__ B2, int K2, int lda2,
    const float* __restrict__ bias, const float* __restrict__ Cin,
    float* __restrict__ C, int Nreal, int Cstride)
{
  __shared__ unsigned short As[128][40];
  __shared__ unsigned short Bs[64][40];
  int tid = threadIdx.x;
  int l = tid & 63, w = tid >> 6;
  int row0 = blockIdx.y * 128, col0 = blockIdx.x * 64;
  int lrow = l & 15, lk = (l >> 4) * 8, lq = (l >> 4) * 4;
  int ar = tid >> 1, asg = (tid & 1) * 16;
  int br = tid >> 2, bsg = (tid & 3) * 8;
  f32x4 acc[2][4] = {};
#pragma unroll 1
  for (int pass = 0; pass < 2; ++pass) {
    const unsigned short* A  = pass ? A2 : A1;
    const unsigned short* Bt = pass ? B2 : B1;
    int K   = pass ? K2 : K1;
    int lda = pass ? lda2 : lda1;
    if (K == 0) break;
    for (int k0 = 0; k0 < K; k0 += 32) {
      const uint4* ga = (const uint4*)(A + (size_t)(row0 + ar) * lda + k0 + asg);
      uint4 a0 = ga[0], a1 = ga[1];
      uint4 b0 = *(const uint4*)(Bt + (size_t)(col0 + br) * K + k0 + bsg);
      __syncthreads();
      *(uint4*)&As[ar][asg]     = a0;
      *(uint4*)&As[ar][asg + 8] = a1;
      *(uint4*)&Bs[br][bsg]     = b0;
      __syncthreads();
      short8 av[2], bv[4];
#pragma unroll
      for (int f = 0; f < 2; ++f)
        av[f] = *(const short8*)&As[w * 32 + f * 16 + lrow][lk];
#pragma unroll
      for (int fc = 0; fc < 4; ++fc)
        bv[fc] = *(const short8*)&Bs[fc * 16 + lrow][lk];
#pragma unroll
      for (int f = 0; f < 2; ++f)
#pragma unroll
        for (int fc = 0; fc < 4; ++fc)
          acc[f][fc] = __builtin_amdgcn_mfma_f32_16x16x32_bf16(av[f], bv[fc], acc[f][fc], 0, 0, 0);
    }
  }
#pragma unroll
  for (int f = 0; f < 2; ++f) {
#pragma unroll
    for (int fc = 0; fc < 4; ++fc) {
      int c = col0 + fc * 16 + lrow;
      if (c < Nreal) {
        float bb = bias ? bias[c] : 0.0f;
#pragma unroll
        for (int i = 0; i < 4; ++i) {
          int r = row0 + w * 32 + f * 16 + lq + i;
          if (r < BT) {
            float v = acc[f][fc][i] + bb;
            if (Cin) v += Cin[(size_t)r * Cstride + c];
            C[(size_t)r * Cstride + c] = v;
          }
        }
      }
    }
  }
}

// ---------------- BiLSTM scan (round-6 verified) ----------------
__global__ __launch_bounds__(512) void k_lstm(
    const float* __restrict__ xp_f, const float* __restrict__ xp_b,
    const uint4* __restrict__ PAQ_f, const uint4* __restrict__ PBQ_f,
    const uint4* __restrict__ PAQ_b, const uint4* __restrict__ PBQ_b,
    const int* __restrict__ lengths, unsigned short* __restrict__ factsh)
{
  int b = blockIdx.x;
  int dir = blockIdx.y;
  const float* xp = dir ? xp_b : xp_f;
  const uint4* PAQ = dir ? PAQ_b : PAQ_f;
  const uint4* PBQ = dir ? PBQ_b : PBQ_f;
  int tid = threadIdx.x;
  int j = tid & 255, half = tid >> 8;
  __shared__ float hs[H];
  __shared__ float4 red[512];
  hs[j] = 0.0f;
  float c = 0.0f, h = 0.0f;
  int nsteps = dir ? T : lengths[b];
  const uint4* pa = PAQ + (size_t)(half * 32) * 256 + j;
  const uint4* pb = PBQ + (size_t)(half * 32) * 256 + j;
  const float4* hs4 = reinterpret_cast<const float4*>(hs) + half * 32;
  __syncthreads();
  for (int s = 0; s < nsteps; ++s) {
    int t = dir ? (T - 1 - s) : s;
    float g0 = 0.f, g1 = 0.f, g2 = 0.f, g3 = 0.f;
#pragma unroll 4
    for (int k4 = 0; k4 < 32; ++k4) {
      uint4 a  = pa[(size_t)k4 * 256];
      uint4 bq = pb[(size_t)k4 * 256];
      float4 hv = hs4[k4];
      g0 = fmaf(hv.x, bf_lo(a.x), g0);  g1 = fmaf(hv.x, bf_hi(a.x), g1);
      g2 = fmaf(hv.x, bf_lo(bq.x), g2); g3 = fmaf(hv.x, bf_hi(bq.x), g3);
      g0 = fmaf(hv.y, bf_lo(a.y), g0);  g1 = fmaf(hv.y, bf_hi(a.y), g1);
      g2 = fmaf(hv.y, bf_lo(bq.y), g2); g3 = fmaf(hv.y, bf_hi(bq.y), g3);
      g0 = fmaf(hv.z, bf_lo(a.z), g0);  g1 = fmaf(hv.z, bf_hi(a.z), g1);
      g2 = fmaf(hv.z, bf_lo(bq.z), g2); g3 = fmaf(hv.z, bf_hi(bq.z), g3);
      g0 = fmaf(hv.w, bf_lo(a.w), g0);  g1 = fmaf(hv.w, bf_hi(a.w), g1);
      g2 = fmaf(hv.w, bf_lo(bq.w), g2); g3 = fmaf(hv.w, bf_hi(bq.w), g3);
    }
    red[tid] = make_float4(g0, g1, g2, g3);
    __syncthreads();
    if (half == 0) {
      float4 o = red[tid + 256];
      const float* xrow = xp + (size_t)(b * T + t) * G4;
      g0 += o.x + xrow[j];
      g1 += o.y + xrow[j + 256];
      g2 += o.z + xrow[j + 512];
      g3 += o.w + xrow[j + 768];
      float ig = sigmoidf(g0);
      float fg = sigmoidf(g1);
      float gg = tanhf_fast(g2);
      float og = sigmoidf(g3);
      c = fg * c + ig * gg;
      h = og * tanhf_fast(c);
      hs[j] = h;
      factsh[(size_t)(b * T + t) * D + dir * H + j] = (unsigned short)bf16rne(h);
    }
    __syncthreads();
  }
}

// ---------------- z halves -> bf16 ----------------
__global__ void k_buildz(const unsigned short* __restrict__ factsh, const float* __restrict__ v,
                         unsigned short* __restrict__ za, unsigned short* __restrict__ zb) {
  int bt = blockIdx.x;
  int b = bt / T;
  int d = threadIdx.x;  // 512
  float f = bfu(factsh[(size_t)bt * D + d]);
  float vv = v[(size_t)b * D + d];
  za[(size_t)bt * D + d] = (unsigned short)bf16rne(f * vv);
  zb[(size_t)bt * D + d] = (unsigned short)bf16rne(fabsf(f - vv));
}

// ---------------- score ----------------
__global__ void k_score(const float* __restrict__ att_h, const float* __restrict__ W2,
                        const float* __restrict__ b2, float* __restrict__ s) {
  int bt = blockIdx.x;
  int tid = threadIdx.x;  // 64
  float acc = 0.f;
  for (int e = tid; e < E; e += 64)
    acc += tanhf_fast(att_h[(size_t)bt * E + e]) * W2[e];
  for (int off = 32; off > 0; off >>= 1) acc += __shfl_down(acc, off);
  if (tid == 0) s[bt] = acc + b2[0];
}

// ---------------- masked softmax ----------------
__global__ void k_softmax(const float* __restrict__ s, const int* __restrict__ lengths,
                          float* __restrict__ a) {
  int b = blockIdx.x;
  int t = threadIdx.x;  // 128
  int len = lengths[b];
  __shared__ float wred[2];
  float val = -1e30f;
  if (t < T) val = (t < len) ? s[b * T + t] : -1e9f;
  float mx = val;
  for (int off = 32; off > 0; off >>= 1) mx = fmaxf(mx, __shfl_xor(mx, off));
  int wid = t >> 6, lane = t & 63;
  if (lane == 0) wred[wid] = mx;
  __syncthreads();
  mx = fmaxf(wred[0], wred[1]);
  __syncthreads();
  float e = (t < T && t < len) ? __expf(val - mx) : 0.0f;
  float sum = e;
  for (int off = 32; off > 0; off >>= 1) sum += __shfl_xor(sum, off);
  if (lane == 0) wred[wid] = sum;
  __syncthreads();
  float tot = wred[0] + wred[1];
  if (t < T) a[b * T + t] = e / tot;
}

// ---------------- zero helpers ----------------
__global__ void k_zero(int* __restrict__ p, int n) {
  int i = blockIdx.x * blockDim.x + threadIdx.x;
  if (i < n) p[i] = 0;
}
__global__ void k_ginit(unsigned short* __restrict__ Hb0) {
  Hb0[blockIdx.x * 512 + threadIdx.x] = 0;
}

// ---------------- persistent GRU hop: 32 blocks x 256 thr, 32KB LDS weights --------
// Identical to round 10 EXCEPT the grid barrier: per-block flag slots (monotonic
// step values) + wave-parallel polling, replacing the serializing atomicAdd on a
// single counter. Arrival = 1 relaxed store to own slot; wait = lanes 0..31 poll
// 32 distinct flags with one load/iteration + 64-bit ballot.
__global__ __launch_bounds__(256) void k_gru_hop(
    const unsigned short* __restrict__ URCT,   // [1024][512] bf16: UrT | UcT
    unsigned short* __restrict__ Hb,           // [2][B][D] bf16, Hb[0] pre-zeroed
    float* __restrict__ ep,
    const unsigned* __restrict__ XRC,          // [BT][D] bf16 pair (xr,xc)
    const float* __restrict__ br, const float* __restrict__ bc,
    const float* __restrict__ att, int* __restrict__ syncA)  // syncA: 32 flag slots
{
  __shared__ unsigned short Wl[32 * 512];      // 32 KB
  const int tid = threadIdx.x;
  const int bi  = blockIdx.x;                  // 0..31
  const int j0  = bi * 16;
  const int w   = tid >> 6;                    // batch group 0..3
  const int l   = tid & 63;
  const int lrow = l & 15, g = l >> 4;
  const int lq  = g * 4;
  const int j   = j0 + lrow;

  // weights -> LDS (16B-unit XOR swizzle)
  for (int it = tid; it < 32 * 64; it += 256) {
    int row = it >> 6, unit = it & 63;
    int grow = (row < 16) ? (j0 + row) : (512 + j0 + row - 16);
    uint4 v = *(const uint4*)(URCT + (size_t)grow * 512 + unit * 8);
    *(uint4*)&Wl[row * 512 + ((unit ^ (row & 7)) * 8)] = v;
  }

  const float brj = br[j], bcj = bc[j];

  // prefetch gate operands for t = 0
  unsigned xq[4];
  float gv[4];
#pragma unroll
  for (int i = 0; i < 4; ++i) {
    int b = w * 16 + lq + i;
    gv[i] = att[b * T];
    xq[i] = XRC[(size_t)(b * T) * D + j];
  }
  __syncthreads();   // weights staged (drains prefetch too — overlapped)

  float h[4] = {};
  for (int t = 0; t < T; ++t) {
    const unsigned short* Hin = Hb + (size_t)(t & 1) * (B * D);
    unsigned short*      Hout = Hb + (size_t)((t + 1) & 1) * (B * D);
    // post-barrier critical path: only the H fragments
    uint4 a[16];
#pragma unroll
    for (int c = 0; c < 16; ++c)
      a[c] = *(const uint4*)(Hin + (size_t)(w * 16 + lrow) * D + c * 32 + g * 8);
    // issue next step's read-only operand loads (hidden under MFMA + barrier drain)
    unsigned xqn[4] = {};
    float gvn[4] = {};
    if (t + 1 < T) {
#pragma unroll
      for (int i = 0; i < 4; ++i) {
        int b = w * 16 + lq + i;
        gvn[i] = att[b * T + t + 1];
        xqn[i] = XRC[(size_t)(b * T + t + 1) * D + j];
      }
    }
    f32x4 acc[2] = {};
#pragma unroll
    for (int c = 0; c < 16; ++c) {
      short8 av = *(const short8*)&a[c];
#pragma unroll
      for (int fc = 0; fc < 2; ++fc) {
        int row = fc * 16 + lrow;
        short8 bv = *(const short8*)&Wl[row * 512 + (((c * 4 + g) ^ (row & 7)) * 8)];
        acc[fc] = __builtin_amdgcn_mfma_f32_16x16x32_bf16(av, bv, acc[fc], 0, 0, 0);
      }
    }
    // fused gate epilogue: racc = acc[0], cacc = acc[1] (same lane/reg)
#pragma unroll
    for (int i = 0; i < 4; ++i) {
      int b = w * 16 + lq + i;
      float r  = sigmoidf(bf_lo(xq[i]) + acc[0][i] + brj);
      float hc = tanhf_fast(bf_hi(xq[i]) + r * acc[1][i] + bcj);
      float hn = gv[i] * hc + (1.f - gv[i]) * h[i];
      h[i] = hn;
      Hout[(size_t)b * D + j] = (unsigned short)bf16rne(hn);
    }
    // grid barrier: contention-free per-block flags + ballot-poll
    __syncthreads();
    if (tid == 0) {
      __threadfence();   // release: Hout stores device-visible before flag
      __hip_atomic_store(&syncA[bi], t + 1, __ATOMIC_RELAXED, __HIP_MEMORY_SCOPE_AGENT);
    }
    if (tid < 64) {
      bool active = tid < 32;
      while (true) {
        int v = active ? __hip_atomic_load(&syncA[tid], __ATOMIC_RELAXED,
                                           __HIP_MEMORY_SCOPE_AGENT)
                       : 0x7fffffff;
        if (__ballot(active && v <= t) == 0ull) break;   // all flags >= t+1
        __builtin_amdgcn_s_sleep(1);
      }
    }
    __syncthreads();
    __threadfence();     // acquire: invalidate before reading next Hin
    // rotate prefetched operands
#pragma unroll
    for (int i = 0; i < 4; ++i) { gv[i] = gvn[i]; xq[i] = xqn[i]; }
  }
#pragma unroll
  for (int i = 0; i < 4; ++i) {
    int b = w * 16 + lq + i;
    ep[(size_t)b * D + j] = h[i];
  }
}

// ---------------- hop projection ----------------
__global__ __launch_bounds__(512) void k_hop(
    const float* __restrict__ m_in, const float* __restrict__ ep,
    const float* __restrict__ q, const float* __restrict__ Whop,
    const float* __restrict__ bhop, float* __restrict__ m_out)
{
  int b = blockIdx.x, j = threadIdx.x;
  __shared__ float av[3 * D];
  av[j]         = m_in[(size_t)b * D + j];
  av[D + j]     = ep[(size_t)b * D + j];
  av[2 * D + j] = q[(size_t)b * D + j];
  __syncthreads();
  float acc = bhop[j];
#pragma unroll 4
  for (int k = 0; k < 3 * D; ++k)
    acc = fmaf(av[k], Whop[(size_t)k * D + j], acc);
  m_out[(size_t)b * D + j] = fmaxf(acc, 0.0f);
}

// ---------------- output ----------------
__global__ void k_out(const float* __restrict__ m, const float* __restrict__ q,
                      const float* __restrict__ Wo, const float* __restrict__ bo,
                      float* __restrict__ out)
{
  int b = blockIdx.x, tid = threadIdx.x;  // 256
  float acc = 0.f;
  for (int k = tid; k < D; k += 256)
    acc += m[(size_t)b * D + k] * Wo[k] + q[(size_t)b * D + k] * Wo[D + k];
  for (int off = 32; off > 0; off >>= 1) acc += __shfl_down(acc, off);
  __shared__ float red[4];
  int wid = tid >> 6, lane = tid & 63;
  if (lane == 0) red[wid] = acc;
  __syncthreads();
  if (tid == 0) {
    float tot = red[0] + red[1] + red[2] + red[3];
    out[b] = 1.0f / (1.0f + __expf(-(tot + bo[0])));
  }
}

extern "C" void kernel_launch(void* const* d_in, const int* in_sizes, int n_in,
                              void* d_out, int out_size, void* d_ws, size_t ws_size,
                              hipStream_t stream)
{
  const int*   tokens  = (const int*)d_in[0];
  const int*   lengths = (const int*)d_in[1];
  const float* emb     = (const float*)d_in[2];
  const float* Wx_f    = (const float*)d_in[3];
  const float* Wh_f    = (const float*)d_in[4];
  const float* b_f     = (const float*)d_in[5];
  const float* Wx_b    = (const float*)d_in[6];
  const float* Wh_b    = (const float*)d_in[7];
  const float* b_b     = (const float*)d_in[8];
  const float* W1      = (const float*)d_in[9];
  const float* b1      = (const float*)d_in[10];
  const float* W2      = (const float*)d_in[11];
  const float* b2      = (const float*)d_in[12];
  const float* Wr      = (const float*)d_in[13];
  const float* Ur      = (const float*)d_in[14];
  const float* br      = (const float*)d_in[15];
  const float* Wc      = (const float*)d_in[16];
  const float* Uc      = (const float*)d_in[17];
  const float* bc      = (const float*)d_in[18];
  const float* q       = (const float*)d_in[19];
  const float* W_hops  = (const float*)d_in[20];
  const float* b_hops  = (const float*)d_in[21];
  const float* Wo      = (const float*)d_in[22];
  const float* bo      = (const float*)d_in[23];
  float* ws = (float*)d_ws;

  // ---- workspace layout ----
  float* p = ws;
  unsigned short* xh = (unsigned short*)p;  p += (size_t)Mp * Ep / 2;
  float* xp_f   = p;  p += (size_t)BT * G4;                                 // later: xr | xc -> XRC
  float* xp_b   = p;  p += (size_t)BT * G4;                                 // later: za | zb
  unsigned short* factsh = (unsigned short*)p;  p += (size_t)Mp * D / 2;
  float* att_h  = p;  p += (size_t)BT * E;
  float* part0  = p;  p += (size_t)BT * E;
  float* scores = p;  p += BT;
  float* att    = p;  p += BT;
  float* m0     = p;  p += (size_t)B * D;
  float* m1     = p;  p += (size_t)B * D;
  float* epb    = p;  p += (size_t)B * D;
  unsigned short* Hb = (unsigned short*)p;  p += (size_t)2 * B * D / 2;     // [2][B][D] bf16
  int* syncA    = (int*)p;  p += 3 * 128;
  uint4* PAQ_f  = (uint4*)p;  p += (size_t)(H / 4) * 256 * 4;
  uint4* PBQ_f  = (uint4*)p;  p += (size_t)(H / 4) * 256 * 4;
  uint4* PAQ_b  = (uint4*)p;  p += (size_t)(H / 4) * 256 * 4;
  uint4* PBQ_b  = (uint4*)p;  p += (size_t)(H / 4) * 256 * 4;
  unsigned short* WxT_f = (unsigned short*)p;  p += (size_t)G4 * Ep / 2;
  unsigned short* WxT_b = (unsigned short*)p;  p += (size_t)G4 * Ep / 2;
  unsigned short* WrT   = (unsigned short*)p;  p += (size_t)D * D / 2;
  unsigned short* WcT   = (unsigned short*)p;  p += (size_t)D * D / 2;
  unsigned short* URCT  = (unsigned short*)p;  p += (size_t)(2 * D) * D / 2; // [1024][512]
  unsigned short* W1T[4];
  for (int c = 0; c < 4; ++c) { W1T[c] = (unsigned short*)p; p += (size_t)Ep * D / 2; }
  float* xr = xp_f;
  float* xc = xp_f + (size_t)BT * D;
  unsigned* XRC = (unsigned*)xr;               // in-place bf16-pair pack over xr
  unsigned short* za = (unsigned short*)xp_b;
  unsigned short* zb = (unsigned short*)xp_b + (size_t)Mp * D;

  // 0) zero barrier flags + pack weights
  k_zero<<<1, 384, 0, stream>>>(syncA, 3 * 128);
  k_pack_lstm<<<(H / 4) * 256 / 256, 256, 0, stream>>>(Wh_f, PAQ_f, PBQ_f);
  k_pack_lstm<<<(H / 4) * 256 / 256, 256, 0, stream>>>(Wh_b, PAQ_b, PBQ_b);
  k_packT<<<G4 * Ep / 256, 256, 0, stream>>>(Wx_f, WxT_f, E, G4, G4, Ep);
  k_packT<<<G4 * Ep / 256, 256, 0, stream>>>(Wx_b, WxT_b, E, G4, G4, Ep);
  k_packT<<<D * D / 256, 256, 0, stream>>>(Wr, WrT, D, D, D, D);
  k_packT<<<D * D / 256, 256, 0, stream>>>(Wc, WcT, D, D, D, D);
  k_packT<<<D * D / 256, 256, 0, stream>>>(Ur, URCT, D, D, D, D);
  k_packT<<<D * D / 256, 256, 0, stream>>>(Uc, URCT + (size_t)D * D, D, D, D, D);
  for (int c = 0; c < 4; ++c)
    k_packT<<<Ep * D / 256, 256, 0, stream>>>(W1 + (size_t)c * D * E, W1T[c], D, E, E, D);

  // 1) embed + input projections (MFMA)
  k_gather<<<BT, 256, 0, stream>>>(tokens, emb, xh);
  k_gemm_mfma<<<dim3(G4 / 64, Mp / 128), 256, 0, stream>>>(
      xh, WxT_f, Ep, Ep, nullptr, nullptr, 0, 0, b_f, nullptr, xp_f, G4, G4);
  k_gemm_mfma<<<dim3(G4 / 64, Mp / 128), 256, 0, stream>>>(
      xh, WxT_b, Ep, Ep, nullptr, nullptr, 0, 0, b_b, nullptr, xp_b, G4, G4);
  // 2) BiLSTM
  k_lstm<<<dim3(B, 2), 512, 0, stream>>>(xp_f, xp_b, PAQ_f, PBQ_f, PAQ_b, PBQ_b, lengths, factsh);
  // 3) hop-invariant precomputes (MFMA); then pack xr/xc -> bf16 pairs in place
  k_gemm_mfma<<<dim3(D / 64, Mp / 128), 256, 0, stream>>>(
      factsh, WrT, D, D, nullptr, nullptr, 0, 0, nullptr, nullptr, xr, D, D);
  k_gemm_mfma<<<dim3(D / 64, Mp / 128), 256, 0, stream>>>(
      factsh, WcT, D, D, nullptr, nullptr, 0, 0, nullptr, nullptr, xc, D, D);
  k_packxrc<<<BT * D / 512, 512, 0, stream>>>(xr, xc, XRC);
  k_buildz<<<BT, 512, 0, stream>>>(factsh, q, za, zb);
  k_gemm_mfma<<<dim3(Ep / 64, Mp / 128), 256, 0, stream>>>(
      za, W1T[0], D, D, zb, W1T[2], D, D, b1, nullptr, part0, E, E);

  // 4) hops
  const float* m_in = q;
  float* mb[2] = {m0, m1};
  for (int i = 0; i < NH; ++i) {
    k_buildz<<<BT, 512, 0, stream>>>(factsh, m_in, za, zb);
    k_gemm_mfma<<<dim3(Ep / 64, Mp / 128), 256, 0, stream>>>(
        za, W1T[1], D, D, zb, W1T[3], D, D, nullptr, part0, att_h, E, E);
    k_score<<<BT, 64, 0, stream>>>(att_h, W2, b2, scores);
    k_softmax<<<B, 128, 0, stream>>>(scores, lengths, att);
    // GRU: single persistent kernel per hop (32 blocks, flag-based barrier)
    k_ginit<<<B * D / 512, 512, 0, stream>>>(Hb);
    k_gru_hop<<<32, 256, 0, stream>>>(URCT, Hb, epb, XRC, br, bc, att, syncA + i * 128);
    k_hop<<<B, 512, 0, stream>>>(m_in, epb, q,
                                 W_hops + (size_t)i * 3 * D * D, b_hops + (size_t)i * D,
                                 mb[i & 1]);
    m_in = mb[i & 1];
  }
  // 5) output
  k_out<<<B, 256, 0, stream>>>(m_in, q, Wo, bo, (float*)d_out);
}